// Round 7
// baseline (102.641 us; speedup 1.0000x reference)
//
#include <hip/hip_runtime.h>
#include <hip/hip_bf16.h>

#define BATCH 4
#define CIN   256
#define CMID  128
#define NPOS  4096
#define EPS   1e-5f

typedef __bf16 bf16;
typedef __attribute__((ext_vector_type(8))) __bf16 bf16x8;
typedef __attribute__((ext_vector_type(4))) __bf16 bf16x4;
typedef __attribute__((ext_vector_type(4))) float  f32x4;

#define MFMA16(a, b, c) __builtin_amdgcn_mfma_f32_16x16x32_bf16((a), (b), (c), 0, 0, 0)

// async global->LDS DMA, 16B per lane, dest = wave-uniform base + lane*16
#define GLDS(gsrc, ldst) \
    __builtin_amdgcn_global_load_lds( \
        (const __attribute__((address_space(1))) void*)(gsrc), \
        (__attribute__((address_space(3))) void*)(ldst), 16, 0, 0)

// counted vmcnt wait (T4): never drain to 0 in the main loop
#define WAITVM(N) asm volatile("s_waitcnt vmcnt(" #N ")" ::: "memory")

// XOR swizzle for 256B rows (16 chunks): chunk ^= row&7.
__device__ __forceinline__ int swz256(int row, int colb) {
    return row * 256 + ((((colb >> 4) ^ (row & 7)) << 4) | (colb & 15));
}
// XOR swizzle for 128B rows (8 chunks): chunk ^= row&7.
__device__ __forceinline__ int swz128(int row, int colb) {
    return row * 128 + ((((colb >> 4) ^ (row & 7)) << 4) | (colb & 15));
}
// 64B-row tiles ([128 c][32 n] bf16): phys chunk = c*4 + (n4 ^ ((c>>1)&3)).
// Spreads 16-consecutive-row column reads across the 8 16B bank-slots (2-way).
__device__ __forceinline__ int cswz(int row, int n4) {
    return (row * 4 + (n4 ^ ((row >> 1) & 3))) * 16;
}

// ---------------------------------------------------------------------------
// KT: x [B][CIN][N] f32  ->  xT [B][N][CIN] bf16   (LDS 64x64 tile transpose)
// ---------------------------------------------------------------------------
__global__ __launch_bounds__(256) void kt_transpose(const float* __restrict__ x,
                                                    bf16* __restrict__ xT) {
    __shared__ float tile[64][65];
    int n0 = blockIdx.x * 64, c0 = blockIdx.y * 64, b = blockIdx.z;
    const float* xp = x + (size_t)b * CIN * NPOS;
    int t = threadIdx.x;
    int lr = t >> 4;
    int lc4 = (t & 15) * 4;
    for (int p = 0; p < 4; ++p) {
        int c = lr + p * 16;
        f32x4 v = *reinterpret_cast<const f32x4*>(xp + (size_t)(c0 + c) * NPOS + n0 + lc4);
        tile[c][lc4 + 0] = v[0]; tile[c][lc4 + 1] = v[1];
        tile[c][lc4 + 2] = v[2]; tile[c][lc4 + 3] = v[3];
    }
    __syncthreads();
    bf16* xtp = xT + (size_t)b * NPOS * CIN;
    int cc = (t & 15) * 4;
    for (int p = 0; p < 4; ++p) {
        int n = (t >> 4) + p * 16;
        bf16x4 o;
        o[0] = (bf16)tile[cc + 0][n]; o[1] = (bf16)tile[cc + 1][n];
        o[2] = (bf16)tile[cc + 2][n]; o[3] = (bf16)tile[cc + 3][n];
        *reinterpret_cast<bf16x4*>(xtp + (size_t)(n0 + n) * CIN + c0 + cc) = o;
    }
}

// ---------------------------------------------------------------------------
// K1: q/k/v = W @ x + b.  grid (32 ntile, 3 which, B).
// ---------------------------------------------------------------------------
__global__ __launch_bounds__(256) void k_qkv(
    const float* __restrict__ Wq, const float* __restrict__ Wk, const float* __restrict__ Wv,
    const float* __restrict__ bq, const float* __restrict__ bk, const float* __restrict__ bv,
    const bf16* __restrict__ xT, bf16* __restrict__ qT, bf16* __restrict__ kT,
    bf16* __restrict__ vC) {
    __shared__ __align__(16) char a_lds[128 * 128];
    __shared__ __align__(16) char b_lds[128 * 128];
    int n0 = blockIdx.x * 128, which = blockIdx.y, b = blockIdx.z;
    const float* W    = which == 0 ? Wq : (which == 1 ? Wk : Wv);
    const float* bias = which == 0 ? bq : (which == 1 ? bk : bv);
    int t = threadIdx.x, lane = t & 63, w = t >> 6, wy = w >> 1, wx = w & 1;
    const bf16* xb = xT + (size_t)b * NPOS * CIN;

    f32x4 acc[4][4] = {};
    for (int k0 = 0; k0 < 256; k0 += 64) {
        __syncthreads();
        for (int i = 0; i < 8; ++i) {
            int idx = t + i * 256;
            int row = idx >> 4, c4 = (idx & 15) * 4;
            f32x4 v = *reinterpret_cast<const f32x4*>(W + (size_t)row * CIN + k0 + c4);
            bf16x4 o; o[0] = (bf16)v[0]; o[1] = (bf16)v[1]; o[2] = (bf16)v[2]; o[3] = (bf16)v[3];
            *reinterpret_cast<bf16x4*>(a_lds + swz128(row, c4 * 2)) = o;
        }
        for (int i = 0; i < 4; ++i) {
            int idx = t + i * 256;
            int row = idx >> 3, cb = (idx & 7) * 16;
            bf16x8 vv = *reinterpret_cast<const bf16x8*>(xb + (size_t)(n0 + row) * CIN + k0 + cb / 2);
            *reinterpret_cast<bf16x8*>(b_lds + swz128(row, cb)) = vv;
        }
        __syncthreads();
        for (int ks = 0; ks < 2; ++ks) {
            int kb = ks * 64 + (lane >> 4) * 16;
            bf16x8 af[4], bfr[4];
            for (int i = 0; i < 4; ++i)
                af[i] = *reinterpret_cast<const bf16x8*>(a_lds + swz128(wy * 64 + i * 16 + (lane & 15), kb));
            for (int j = 0; j < 4; ++j)
                bfr[j] = *reinterpret_cast<const bf16x8*>(b_lds + swz128(wx * 64 + j * 16 + (lane & 15), kb));
            for (int i = 0; i < 4; ++i)
                for (int j = 0; j < 4; ++j)
                    acc[i][j] = MFMA16(af[i], bfr[j], acc[i][j]);
        }
    }
    int rg = lane >> 4, cl = lane & 15;
    for (int i = 0; i < 4; ++i) {
        int ch0 = wy * 64 + i * 16 + rg * 4;
        f32x4 bv4 = *reinterpret_cast<const f32x4*>(bias + ch0);
        for (int j = 0; j < 4; ++j) {
            int n = n0 + wx * 64 + j * 16 + cl;
            f32x4 d = acc[i][j];
            for (int r = 0; r < 4; ++r) d[r] += bv4[r];
            if (which == 2) {
                for (int r = 0; r < 4; ++r)
                    vC[((size_t)b * CMID + ch0 + r) * NPOS + n] = (bf16)d[r];
            } else {
                bf16x4 o; o[0] = (bf16)d[0]; o[1] = (bf16)d[1]; o[2] = (bf16)d[2]; o[3] = (bf16)d[3];
                bf16* dst = (which == 0 ? qT : kT);
                *reinterpret_cast<bf16x4*>(dst + ((size_t)b * NPOS + n) * CMID + ch0) = o;
            }
        }
    }
}

// ---------------------------------------------------------------------------
// K2: zpart[mq][b][n] = sum_{m in eighth mq} exp(S[n,m]).
// grid (32 ntile, 8 mq, B), 4 blocks/CU.  k-frags in regs; q staged via DMA
// into 3-deep LDS ring, counted vmcnt (drain only at last step).
// ---------------------------------------------------------------------------
__global__ __launch_bounds__(256, 4) void k_zrow(const bf16* __restrict__ qT,
                                                 const bf16* __restrict__ kT,
                                                 float* __restrict__ zpart) {
    __shared__ __align__(16) char q_lds[3 * 8192];  // [32 m][128 c] swz256
    int n0 = blockIdx.x * 128, mq = blockIdx.y, b = blockIdx.z;
    int t = threadIdx.x, lane = t & 63, w = t >> 6;
    int cl = lane & 15, g = lane >> 4;
    const bf16* qb = qT + (size_t)b * NPOS * CMID;
    const bf16* kb = kT + (size_t)b * NPOS * CMID;

    auto stage_q = [&](int buf, int m0) {
        #pragma unroll
        for (int i = 0; i < 2; ++i) {
            int lc = (w * 2 + i) * 64 + lane;        // chunk idx 0..511
            int r = lc >> 4, p = lc & 15;
            GLDS(qb + (size_t)(m0 + r) * CMID + ((p ^ (r & 7)) << 3),
                 q_lds + buf * 8192 + (w * 2 + i) * 1024);
        }
    };

    // k fragments (B-operand): wave owns n = n0 + w*32 + jn*16 + cl
    bf16x8 kreg[2][4];
    for (int jn = 0; jn < 2; ++jn)
        for (int ks = 0; ks < 4; ++ks)
            kreg[jn][ks] = *reinterpret_cast<const bf16x8*>(
                kb + (size_t)(n0 + w * 32 + jn * 16 + cl) * CMID + ks * 32 + g * 8);

    int mbeg = mq * (NPOS / 8);
    stage_q(0, mbeg);
    stage_q(1, mbeg + 32);
    const int NS = (NPOS / 8) / 32;                  // 16
    int cur = 0, nxt = 2;
    float zacc[2] = {0.f, 0.f};
    for (int s = 0; s < NS; ++s) {
        if (s < NS - 1) { WAITVM(2); } else { WAITVM(0); }   // own stage(s) landed
        asm volatile("" ::: "memory");
        __builtin_amdgcn_s_barrier();                // everyone's stage(s) landed
        asm volatile("" ::: "memory");
        if (s + 2 < NS) stage_q(nxt, mbeg + (s + 2) * 32);  // safe: all past step s-1
        const char* qbuf = q_lds + cur * 8192;
        f32x4 acc[2][2] = {};                        // D[m im][n jn]
        __builtin_amdgcn_s_setprio(1);
        for (int ks = 0; ks < 4; ++ks) {
            bf16x8 qf[2];
            for (int im = 0; im < 2; ++im)
                qf[im] = *reinterpret_cast<const bf16x8*>(qbuf + swz256(im * 16 + cl, ks * 64 + g * 16));
            for (int im = 0; im < 2; ++im)
                for (int jn = 0; jn < 2; ++jn)
                    acc[im][jn] = MFMA16(qf[im], kreg[jn][ks], acc[im][jn]);
        }
        __builtin_amdgcn_s_setprio(0);
        for (int im = 0; im < 2; ++im)
            for (int jn = 0; jn < 2; ++jn)
                for (int r = 0; r < 4; ++r)
                    zacc[jn] += __expf(acc[im][jn][r]);
        cur = (cur == 2) ? 0 : cur + 1;
        nxt = (nxt == 2) ? 0 : nxt + 1;
    }
    for (int jn = 0; jn < 2; ++jn) {
        zacc[jn] += __shfl_xor(zacc[jn], 16);
        zacc[jn] += __shfl_xor(zacc[jn], 32);
    }
    if (g == 0) {
        float* zp = zpart + ((size_t)mq * BATCH + b) * NPOS;
        zp[n0 + w * 32 + cl]      = zacc[0];
        zp[n0 + w * 32 + 16 + cl] = zacc[1];
    }
}

// ---------------------------------------------------------------------------
// K3: invZ = 1 / sum_{s<8} zpart[s].
// ---------------------------------------------------------------------------
__global__ __launch_bounds__(256) void k_rcp(const float* __restrict__ zpart,
                                             float* __restrict__ invZ) {
    int i = (blockIdx.x * 256 + threadIdx.x) * 4;
    f32x4 s = {0.f, 0.f, 0.f, 0.f};
    for (int p = 0; p < 8; ++p) {
        f32x4 a = *reinterpret_cast<const f32x4*>(zpart + (size_t)p * BATCH * NPOS + i);
        for (int r = 0; r < 4; ++r) s[r] += a[r];
    }
    f32x4 o;
    for (int r = 0; r < 4; ++r) o[r] = 1.f / s[r];
    *reinterpret_cast<f32x4*>(invZ + i) = o;
}

// ---------------------------------------------------------------------------
// K3b: vC[c,n] *= invZ[n]  (in-place; vC rebuilt by k_qkv every call).
// ---------------------------------------------------------------------------
__global__ __launch_bounds__(256) void k_vscale(bf16* __restrict__ vC,
                                                const float* __restrict__ invZ) {
    int idx = blockIdx.x * 256 + threadIdx.x;
    int b = idx >> 16;
    int n8 = idx & (NPOS / 8 - 1);
    bf16x8 v = *reinterpret_cast<const bf16x8*>(vC + (size_t)idx * 8);
    const float* iz = invZ + (size_t)b * NPOS + n8 * 8;
    f32x4 i0 = *reinterpret_cast<const f32x4*>(iz);
    f32x4 i1 = *reinterpret_cast<const f32x4*>(iz + 4);
    bf16x8 o;
    for (int r = 0; r < 4; ++r) {
        o[r]     = (bf16)((float)v[r]     * i0[r]);
        o[r + 4] = (bf16)((float)v[r + 4] * i1[r]);
    }
    *reinterpret_cast<bf16x8*>(vC + (size_t)idx * 8) = o;
}

// ---------------------------------------------------------------------------
// K4: y[m][c] = sum_n exp(S[n,m]) vs[c,n]  (vs = invZ-prescaled v).
// grid (32 mtile(128), 4 nq, B), 2 blocks/CU.  32-n steps; k/v staged via DMA
// into 3-deep LDS rings with distance-2 prefetch + counted vmcnt(4) (T4);
// raw s_barrier once per step; m-split PV keeps P wave-private (no extra
// barrier); setprio(1) around both MFMA clusters (T5).  LDS 56KB.
// ---------------------------------------------------------------------------
__global__ __launch_bounds__(256, 2) void k_attn(const bf16* __restrict__ qT,
                                                 const bf16* __restrict__ kT,
                                                 const bf16* __restrict__ vS,
                                                 bf16* __restrict__ ypA,
                                                 bf16* __restrict__ ypB) {
    __shared__ __align__(16) char k_lds[3 * 8192];  // [32 n][128 c] swz256 ring
    __shared__ __align__(16) char v_lds[3 * 8192];  // [128 c][32 n] cswz ring
    __shared__ __align__(16) char p_lds[8192];      // [128 m][32 n] cswz
    int m0 = blockIdx.x * 128, nq = blockIdx.y, b = blockIdx.z;
    int t = threadIdx.x, lane = t & 63, w = t >> 6;
    int cl = lane & 15, g = lane >> 4;
    const bf16* qb = qT + (size_t)b * NPOS * CMID;
    const bf16* kb = kT + (size_t)b * NPOS * CMID;
    const bf16* vb = vS + (size_t)b * CMID * NPOS;

    auto stage_kv = [&](int buf, int n0) {
        #pragma unroll
        for (int i = 0; i < 2; ++i) {
            int lc = (w * 2 + i) * 64 + lane;        // chunk idx 0..511
            int kr = lc >> 4, kp = lc & 15;          // k: 16 chunks/row
            GLDS(kb + (size_t)(n0 + kr) * CMID + ((kp ^ (kr & 7)) << 3),
                 k_lds + buf * 8192 + (w * 2 + i) * 1024);
            int vc = lc >> 2;                        // v: 4 chunks/row
            int vn4 = (lc & 3) ^ ((vc >> 1) & 3);    // inverse of cswz
            GLDS(vb + (size_t)vc * NPOS + n0 + vn4 * 8,
                 v_lds + buf * 8192 + (w * 2 + i) * 1024);
        }
    };

    // q fragments (B-operand): wave owns m-cols m0 + w*32 + jm*16 + cl
    bf16x8 qreg[2][4];
    for (int jm = 0; jm < 2; ++jm)
        for (int ks = 0; ks < 4; ++ks)
            qreg[jm][ks] = *reinterpret_cast<const bf16x8*>(
                qb + (size_t)(m0 + w * 32 + jm * 16 + cl) * CMID + ks * 32 + g * 8);

    f32x4 acc2[2][8] = {};                           // y[m: wave's 32][c: 128]
    int nbeg = nq * (NPOS / 4);
    stage_kv(0, nbeg);
    stage_kv(1, nbeg + 32);
    const int NS = (NPOS / 4) / 32;                  // 32
    int cur = 0, nxt = 2;
    for (int s = 0; s < NS; ++s) {
        int n0 = nbeg + s * 32;
        if (s < NS - 1) { WAITVM(4); } else { WAITVM(0); }   // own stage(s) landed
        asm volatile("" ::: "memory");
        __builtin_amdgcn_s_barrier();                // all stages(s) landed; all
        asm volatile("" ::: "memory");               // reads of buf nxt finished
        if (s + 2 < NS) stage_kv(nxt, n0 + 64);
        const char* kbuf = k_lds + cur * 8192;
        const char* vbuf = v_lds + cur * 8192;
        // S^T: acc1[in][jm] = D[n = in*16+g*4+r][m = w*32+jm*16+cl]
        f32x4 acc1[2][2] = {};
        __builtin_amdgcn_s_setprio(1);
        for (int ks = 0; ks < 4; ++ks) {
            bf16x8 kf[2];
            for (int in = 0; in < 2; ++in)
                kf[in] = *reinterpret_cast<const bf16x8*>(kbuf + swz256(in * 16 + cl, ks * 64 + g * 16));
            for (int in = 0; in < 2; ++in)
                for (int jm = 0; jm < 2; ++jm)
                    acc1[in][jm] = MFMA16(kf[in], qreg[jm][ks], acc1[in][jm]);
        }
        __builtin_amdgcn_s_setprio(0);
        // P^T[m][n] = exp(S), wave-private rows; n = in*16 + g*4 + r.
        for (int in = 0; in < 2; ++in)
            for (int jm = 0; jm < 2; ++jm) {
                int m = w * 32 + jm * 16 + cl;
                bf16x4 o;
                for (int r = 0; r < 4; ++r) o[r] = (bf16)__expf(acc1[in][jm][r]);
                *reinterpret_cast<bf16x4*>(p_lds + cswz(m, in * 2 + (g >> 1)) + (g & 1) * 8) = o;
            }
        // PV: A = own P rows (K=32 = whole step), B = v c-tiles.
        bf16x8 af[2];
        for (int jm = 0; jm < 2; ++jm)
            af[jm] = *reinterpret_cast<const bf16x8*>(p_lds + cswz(w * 32 + jm * 16 + cl, g));
        __builtin_amdgcn_s_setprio(1);
        for (int j = 0; j < 8; ++j) {
            bf16x8 vf = *reinterpret_cast<const bf16x8*>(vbuf + cswz(j * 16 + cl, g));
            for (int jm = 0; jm < 2; ++jm)
                acc2[jm][j] = MFMA16(af[jm], vf, acc2[jm][j]);
        }
        __builtin_amdgcn_s_setprio(0);
        cur = (cur == 2) ? 0 : cur + 1;
        nxt = (nxt == 2) ? 0 : nxt + 1;
    }
    bf16* yb = ((nq & 2) ? ypB : ypA) + ((size_t)(nq & 1) * BATCH + b) * NPOS * CMID
             + (size_t)m0 * CMID;
    for (int jm = 0; jm < 2; ++jm)
        for (int j = 0; j < 8; ++j) {
            int c = j * 16 + cl;
            for (int r = 0; r < 4; ++r) {
                int m = w * 32 + jm * 16 + g * 4 + r;
                yb[(size_t)m * CMID + c] = (bf16)acc2[jm][j][r];
            }
        }
}

// ---------------------------------------------------------------------------
// K5: out = (Ww @ sum(y-slices) + bw)*inv + add + x. grid (64 mtile,2 otile,B)
// m-tile 64 -> 512 blocks = 2/CU.
// ---------------------------------------------------------------------------
__global__ __launch_bounds__(256) void k_out(
    const float* __restrict__ Ww, const float* __restrict__ bw,
    const float* __restrict__ gamma, const float* __restrict__ beta,
    const float* __restrict__ mean, const float* __restrict__ var,
    const bf16* __restrict__ ypA, const bf16* __restrict__ ypB,
    const float* __restrict__ x, float* __restrict__ out) {
    __shared__ __align__(16) char a_lds[128 * 128];  // [128 o][64 c] bf16 swz
    __shared__ __align__(16) char b_lds[64 * 128];   // [64 m][64 c] bf16 swz
    int m0 = blockIdx.x * 64, o0 = blockIdx.y * 128, b = blockIdx.z;
    int t = threadIdx.x, lane = t & 63, w = t >> 6, wy = w >> 1, wx = w & 1;
    size_t boff = (size_t)b * NPOS * CMID;
    const bf16* y0 = ypA + boff;
    const bf16* y1 = ypA + (size_t)BATCH * NPOS * CMID + boff;
    const bf16* y2 = ypB + boff;
    const bf16* y3 = ypB + (size_t)BATCH * NPOS * CMID + boff;
    f32x4 acc[4][2] = {};
    for (int k0 = 0; k0 < 128; k0 += 64) {
        __syncthreads();
        for (int i = 0; i < 8; ++i) {
            int idx = t + i * 256, row = idx >> 4, c4 = (idx & 15) * 4;
            f32x4 v = *reinterpret_cast<const f32x4*>(Ww + (size_t)(o0 + row) * CMID + k0 + c4);
            bf16x4 o; o[0] = (bf16)v[0]; o[1] = (bf16)v[1]; o[2] = (bf16)v[2]; o[3] = (bf16)v[3];
            *reinterpret_cast<bf16x4*>(a_lds + swz128(row, c4 * 2)) = o;
        }
        for (int i = 0; i < 4; ++i) {
            int idx = t + i * 256, row = idx >> 4, c4 = (idx & 15) * 4;
            size_t yoff = (size_t)(m0 + row) * CMID + k0 + c4;
            bf16x4 a0 = *reinterpret_cast<const bf16x4*>(y0 + yoff);
            bf16x4 a1 = *reinterpret_cast<const bf16x4*>(y1 + yoff);
            bf16x4 a2 = *reinterpret_cast<const bf16x4*>(y2 + yoff);
            bf16x4 a3 = *reinterpret_cast<const bf16x4*>(y3 + yoff);
            bf16x4 o;
            for (int r = 0; r < 4; ++r)
                o[r] = (bf16)((float)a0[r] + (float)a1[r] + (float)a2[r] + (float)a3[r]);
            *reinterpret_cast<bf16x4*>(b_lds + swz128(row, c4 * 2)) = o;
        }
        __syncthreads();
        for (int ks = 0; ks < 2; ++ks) {
            int kb = ks * 64 + (lane >> 4) * 16;
            bf16x8 af[4], bfr[2];
            for (int i = 0; i < 4; ++i)
                af[i] = *reinterpret_cast<const bf16x8*>(a_lds + swz128(wy * 64 + i * 16 + (lane & 15), kb));
            for (int j = 0; j < 2; ++j)
                bfr[j] = *reinterpret_cast<const bf16x8*>(b_lds + swz128(wx * 32 + j * 16 + (lane & 15), kb));
            for (int i = 0; i < 4; ++i)
                for (int j = 0; j < 2; ++j)
                    acc[i][j] = MFMA16(af[i], bfr[j], acc[i][j]);
        }
    }
    int rg = lane >> 4, cl = lane & 15;
    const float* xb = x + (size_t)b * CIN * NPOS;
    float* ob = out + (size_t)b * CIN * NPOS;
    for (int i = 0; i < 4; ++i) {
        int och0 = o0 + wy * 64 + i * 16 + rg * 4;
        f32x4 gg = *reinterpret_cast<const f32x4*>(gamma + och0);
        f32x4 be = *reinterpret_cast<const f32x4*>(beta + och0);
        f32x4 mu = *reinterpret_cast<const f32x4*>(mean + och0);
        f32x4 va = *reinterpret_cast<const f32x4*>(var + och0);
        f32x4 bb = *reinterpret_cast<const f32x4*>(bw + och0);
        float invv[4], addv[4];
        for (int r = 0; r < 4; ++r) {
            invv[r] = gg[r] / sqrtf(va[r] + EPS);
            addv[r] = be[r] - mu[r] * invv[r];
        }
        for (int j = 0; j < 2; ++j) {
            int m = m0 + wx * 32 + j * 16 + cl;
            for (int r = 0; r < 4; ++r) {
                float z = (acc[i][j][r] + bb[r]) * invv[r] + addv[r];
                ob[(size_t)(och0 + r) * NPOS + m] = z + xb[(size_t)(och0 + r) * NPOS + m];
            }
        }
    }
}

// ---------------------------------------------------------------------------
extern "C" void kernel_launch(void* const* d_in, const int* in_sizes, int n_in,
                              void* d_out, int out_size, void* d_ws, size_t ws_size,
                              hipStream_t stream) {
    const float* x     = (const float*)d_in[0];
    const float* Wq    = (const float*)d_in[1];
    const float* bq    = (const float*)d_in[2];
    const float* Wk    = (const float*)d_in[3];
    const float* bk    = (const float*)d_in[4];
    const float* Wv    = (const float*)d_in[5];
    const float* bv    = (const float*)d_in[6];
    const float* Ww    = (const float*)d_in[7];
    const float* bw    = (const float*)d_in[8];
    const float* gamma = (const float*)d_in[9];
    const float* beta  = (const float*)d_in[10];
    const float* mean  = (const float*)d_in[11];
    const float* var   = (const float*)d_in[12];
    float* out = (float*)d_out;

    char* ws = (char*)d_ws;
    char* regionA = ws;                    ws += (size_t)BATCH * NPOS * CIN * 2;   // 8 MB
    bf16* qT = (bf16*)ws;                  ws += (size_t)BATCH * NPOS * CMID * 2;  // 4 MB
    bf16* kT = (bf16*)ws;                  ws += (size_t)BATCH * NPOS * CMID * 2;  // 4 MB
    bf16* vC = (bf16*)ws;                  ws += (size_t)BATCH * NPOS * CMID * 2;  // 4 MB
    bf16* ypB = (bf16*)ws;                 ws += (size_t)2 * BATCH * NPOS * CMID * 2; // 8 MB
    float* zpart = (float*)ws;             ws += (size_t)8 * BATCH * NPOS * 4;     // 512 KB
    float* invZ = (float*)ws;
    bf16* xT  = (bf16*)regionA;
    bf16* ypA = (bf16*)regionA;            // valid once k_qkv no longer needs xT

    kt_transpose<<<dim3(NPOS / 64, CIN / 64, BATCH), 256, 0, stream>>>(x, xT);
    k_qkv<<<dim3(NPOS / 128, 3, BATCH), 256, 0, stream>>>(Wq, Wk, Wv, bq, bk, bv, xT, qT, kT, vC);
    k_zrow<<<dim3(NPOS / 128, 8, BATCH), 256, 0, stream>>>(qT, kT, zpart);
    k_rcp<<<dim3(BATCH * NPOS / 1024), 256, 0, stream>>>(zpart, invZ);
    k_vscale<<<dim3(BATCH * CMID * NPOS / 8 / 256), 256, 0, stream>>>(vC, invZ);
    k_attn<<<dim3(NPOS / 128, 4, BATCH), 256, 0, stream>>>(qT, kT, vC, ypA, ypB);
    k_out<<<dim3(NPOS / 64, 2, BATCH), 256, 0, stream>>>(Ww, bw, gamma, beta, mean, var, ypA, ypB, x, out);
}